// Round 14
// baseline (121.501 us; speedup 1.0000x reference)
//
#include <hip/hip_runtime.h>
#include <stdint.h>

// OKRRouter, split-bf16 MFMA, 3 slim kernels.
// K2 gemm_r: ZERO-LDS, ZERO-BARRIER register-everything GEMM (round-12/13 ablations showed
//   LDS-staged variants stall on ds_read<->gl_lds port contention; comp-only=24.7us but
//   full=60us). Wave owns 64 tokens (4 M-tiles) x K-quarter: 96 MFMA per 24 loads (4:1).
//   1 wave/SIMD with full 512-VGPR budget (launch_bounds(256,1)); NTS=16 fully unrolled ->
//   SSA arrays; loads for step ts+1 issued before compute of step ts (one-step window
//   ~3200 cyc >> 900-cyc HBM latency, compiler emits counted vmcnt per m131).
// K3 router_k: 1 wave/token; sums 4 partials; margin-guarded exact fp32 recompute
//   (validated rounds 3-13).

#define DDIM 2048
#define NEXP 64
#define KSPL 4
#define NTS  16
#define NEG_INF  -1000000000.0f
#define MRG_RAW  0.04f
#define MRG_WM   0.15f

typedef __attribute__((ext_vector_type(8))) short bf16x8;
typedef __attribute__((ext_vector_type(4))) float f32x4;

union BFrag { bf16x8 v; f32x4 f; uint32_t w[4]; uint4 q; };

__device__ inline void split8_rne(const float* a, bf16x8* hi, bf16x8* lo) {
    BFrag h, l;
    #pragma unroll
    for (int p = 0; p < 4; ++p) {
        const uint32_t u0 = __float_as_uint(a[2*p]);
        const uint32_t u1 = __float_as_uint(a[2*p+1]);
        const uint32_t h0 = (u0 + 0x7FFFu + ((u0 >> 16) & 1u)) >> 16;
        const uint32_t h1 = (u1 + 0x7FFFu + ((u1 >> 16) & 1u)) >> 16;
        const float r0 = a[2*p]   - __uint_as_float(h0 << 16);
        const float r1 = a[2*p+1] - __uint_as_float(h1 << 16);
        const uint32_t v0 = __float_as_uint(r0);
        const uint32_t v1 = __float_as_uint(r1);
        const uint32_t l0 = (v0 + 0x7FFFu + ((v0 >> 16) & 1u)) >> 16;
        const uint32_t l1 = (v1 + 0x7FFFu + ((v1 >> 16) & 1u)) >> 16;
        h.w[p] = h0 | (h1 << 16);
        l.w[p] = l0 | (l1 << 16);
    }
    *hi = h.v; *lo = l.v;
}

__device__ inline void split8t(const float* a, bf16x8* hi, bf16x8* lo) {
    BFrag h, l;
    #pragma unroll
    for (int p = 0; p < 4; ++p) {
        const uint32_t u0 = __float_as_uint(a[2*p]);
        const uint32_t u1 = __float_as_uint(a[2*p+1]);
        h.w[p] = (u0 >> 16) | (u1 & 0xFFFF0000u);
        const float r0 = a[2*p]   - __uint_as_float(u0 & 0xFFFF0000u);
        const float r1 = a[2*p+1] - __uint_as_float(u1 & 0xFFFF0000u);
        l.w[p] = (__float_as_uint(r0) >> 16) | (__float_as_uint(r1) & 0xFFFF0000u);
    }
    *hi = h.v; *lo = l.v;
}

// ---- K1: B' fragments, lane-linear: uint4 index = (kstep*8+s)*128 + hl*64 + lane ----
// lane l of frag (kstep,s,hl) holds B[kstep*32 + (l>>4)*8 + j][s*16 + (l&15)], j=0..7
__global__ void prep_b(const float* __restrict__ gateW, const float* __restrict__ secret,
                       uint4* __restrict__ wsB) {
    const int kstep = blockIdx.x;
    const int s = threadIdx.x >> 6;
    const int l = threadIdx.x & 63;
    const int col = s * 16 + (l & 15);
    const int kb  = kstep * 32 + (l >> 4) * 8;
    float v[8];
    if (col < NEXP) {
        #pragma unroll
        for (int j = 0; j < 8; ++j) v[j] = gateW[(size_t)col * DDIM + kb + j];
    } else {
        #pragma unroll
        for (int j = 0; j < 8; ++j) v[j] = secret[(size_t)(kb + j) * NEXP + (col - NEXP)];
    }
    bf16x8 hi, lo; split8_rne(v, &hi, &lo);
    const size_t base = (size_t)(kstep * 8 + s) * 128 + l;
    BFrag t;
    t.v = hi; wsB[base]      = t.q;
    t.v = lo; wsB[base + 64] = t.q;
}

// ---- K2: register-everything GEMM ----
__global__ __launch_bounds__(256, 1)   // 1 wave/SIMD -> full 512-VGPR budget
void gemm_r(const float* __restrict__ x, const uint4* __restrict__ wsB,
            float* __restrict__ wsP, int ntok)
{
    const int tid = threadIdx.x;
    const int w = tid >> 6, l = tid & 63;
    const int c = l & 15;              // token within 16-tile / frag col
    const int g = l >> 4;              // k-group / C-row group
    const int q  = blockIdx.x & (KSPL - 1);
    const int mb = blockIdx.x / KSPL;
    const int wrow = mb * 256 + w * 64;    // wave token base (4 M-tiles of 16)

    f32x4 acc[4][8];
    #pragma unroll
    for (int m = 0; m < 4; ++m)
        #pragma unroll
        for (int s = 0; s < 8; ++s) acc[m][s] = (f32x4){0.f, 0.f, 0.f, 0.f};

    // per-lane A row pointer for M-tile m: rows wrow + m*16 + c
    const float* xr = x + (size_t)(wrow + c) * DDIM + q * (DDIM / KSPL) + g * 8;
    const uint4* bp = wsB + (size_t)(q * NTS * 8) * 128 + l;

    // SSA pipeline arrays (constant-indexed after full unroll)
    float4 Aa[NTS + 1][4], Ab[NTS + 1][4];
    BFrag  BH[NTS + 1][8], BL[NTS + 1][8];

    // prologue: loads for step 0
    #pragma unroll
    for (int m = 0; m < 4; ++m) {
        const float* xm = xr + (size_t)(m * 16) * DDIM;
        Aa[0][m] = *reinterpret_cast<const float4*>(xm);
        Ab[0][m] = *reinterpret_cast<const float4*>(xm + 4);
    }
    #pragma unroll
    for (int s = 0; s < 8; ++s) {
        BH[0][s].q = bp[(size_t)s * 128];
        BL[0][s].q = bp[(size_t)s * 128 + 64];
    }

    #pragma unroll
    for (int ts = 0; ts < NTS; ++ts) {
        // issue next step's loads first (clamped dummy at tail keeps shape uniform)
        const int nx = (ts + 1 < NTS) ? ts + 1 : ts;
        #pragma unroll
        for (int m = 0; m < 4; ++m) {
            const float* xm = xr + (size_t)(m * 16) * DDIM + nx * 32;
            Aa[ts + 1][m] = *reinterpret_cast<const float4*>(xm);
            Ab[ts + 1][m] = *reinterpret_cast<const float4*>(xm + 4);
        }
        #pragma unroll
        for (int s = 0; s < 8; ++s) {
            BH[ts + 1][s].q = bp[(size_t)(nx * 8 + s) * 128];
            BL[ts + 1][s].q = bp[(size_t)(nx * 8 + s) * 128 + 64];
        }

        // compute step ts (compiler waits only on step-ts loads; ts+1 stays in flight)
        bf16x8 ah[4], al[4];
        #pragma unroll
        for (int m = 0; m < 4; ++m) {
            const float va[8] = {Aa[ts][m].x, Aa[ts][m].y, Aa[ts][m].z, Aa[ts][m].w,
                                 Ab[ts][m].x, Ab[ts][m].y, Ab[ts][m].z, Ab[ts][m].w};
            split8t(va, &ah[m], &al[m]);
        }

        #pragma unroll
        for (int s = 0; s < 8; ++s)
            #pragma unroll
            for (int m = 0; m < 4; ++m) {
                acc[m][s] = __builtin_amdgcn_mfma_f32_16x16x32_bf16(ah[m], BH[ts][s].v, acc[m][s], 0, 0, 0);
                acc[m][s] = __builtin_amdgcn_mfma_f32_16x16x32_bf16(ah[m], BL[ts][s].v, acc[m][s], 0, 0, 0);
                acc[m][s] = __builtin_amdgcn_mfma_f32_16x16x32_bf16(al[m], BH[ts][s].v, acc[m][s], 0, 0, 0);
            }
    }

    // partials: C/D layout row = (l>>4)*4 + reg, col = l&15
    const size_t MN = (size_t)ntok * 128;
    #pragma unroll
    for (int m = 0; m < 4; ++m)
        #pragma unroll
        for (int s = 0; s < 8; ++s)
            #pragma unroll
            for (int r = 0; r < 4; ++r)
                wsP[(size_t)q * MN + (size_t)(wrow + m * 16 + g * 4 + r) * 128 + s * 16 + c]
                    = acc[m][s][r];
}

// ---- K3: router, 1 wave per token, sums KSPL partials (validated rounds 2-13) ----
template <int KSPLIT>
__global__ __launch_bounds__(256, 4)
void router_k(const float* __restrict__ wsP,
              const float* __restrict__ x,
              const float* __restrict__ gateW,
              const float* __restrict__ secret,
              float* __restrict__ out, int ntok)
{
    const int t = blockIdx.x * 4 + (threadIdx.x >> 6);
    const int e = threadIdx.x & 63;
    const size_t MN = (size_t)ntok * 128;

    float raw = 0.f, wm = 0.f;
    #pragma unroll
    for (int q = 0; q < KSPLIT; ++q) {
        raw += wsP[(size_t)q * MN + (size_t)t * 128 + e];
        wm  += wsP[(size_t)q * MN + (size_t)t * 128 + NEXP + e];
    }

    float rmax = raw;
    #pragma unroll
    for (int off = 32; off; off >>= 1) rmax = fmaxf(rmax, __shfl_xor(rmax, off));

    // guard 1: safe-mask boundary margin -> exact fp32 raw recompute (whole token)
    if (__any(fabsf(raw - (rmax - 1.5f)) < MRG_RAW)) {
        float s0 = 0.f, s1 = 0.f, s2 = 0.f, s3 = 0.f;
        const float4* xr = reinterpret_cast<const float4*>(x + (size_t)t * DDIM);
        const float4* wr = reinterpret_cast<const float4*>(gateW + (size_t)e * DDIM);
        for (int k = 0; k < DDIM / 4; ++k) {
            const float4 a = xr[k], b = wr[k];
            s0 = fmaf(a.x, b.x, s0); s1 = fmaf(a.y, b.y, s1);
            s2 = fmaf(a.z, b.z, s2); s3 = fmaf(a.w, b.w, s3);
        }
        raw = (s0 + s1) + (s2 + s3);
        rmax = raw;
        #pragma unroll
        for (int off = 32; off; off >>= 1) rmax = fmaxf(rmax, __shfl_xor(rmax, off));
    }

    const bool safe = (raw >= rmax - 1.5f);
    float m = safe ? wm : NEG_INF;

    // top-3 (value desc, lowest index on ties = jax.lax.top_k)
    float v1 = m; int e1 = e;
    #pragma unroll
    for (int off = 32; off; off >>= 1) {
        const float ov = __shfl_xor(v1, off); const int oi = __shfl_xor(e1, off);
        if (ov > v1 || (ov == v1 && oi < e1)) { v1 = ov; e1 = oi; }
    }
    float v2 = (e == e1) ? -3.0e38f : m; int e2 = e;
    #pragma unroll
    for (int off = 32; off; off >>= 1) {
        const float ov = __shfl_xor(v2, off); const int oi = __shfl_xor(e2, off);
        if (ov > v2 || (ov == v2 && oi < e2)) { v2 = ov; e2 = oi; }
    }
    float v3 = (e == e1 || e == e2) ? -3.0e38f : m; int e3 = e;
    #pragma unroll
    for (int off = 32; off; off >>= 1) {
        const float ov = __shfl_xor(v3, off); const int oi = __shfl_xor(e3, off);
        if (ov > v3 || (ov == v3 && oi < e3)) { v3 = ov; e3 = oi; }
    }

    // guard 2: close wm ordering among safe candidates -> exact fp32 wm recompute
    const bool wmRisk = (v2 > NEG_INF + 1.0f && v1 - v2 < MRG_WM) ||
                        (v3 > NEG_INF + 1.0f && v2 - v3 < MRG_WM);
    if (__any(wmRisk)) {
        float s0 = 0.f, s1 = 0.f, s2 = 0.f, s3 = 0.f;
        const float* xr = x + (size_t)t * DDIM;
        for (int k = 0; k < DDIM; k += 4) {
            s0 = fmaf(xr[k + 0], secret[(size_t)(k + 0) * NEXP + e], s0);
            s1 = fmaf(xr[k + 1], secret[(size_t)(k + 1) * NEXP + e], s1);
            s2 = fmaf(xr[k + 2], secret[(size_t)(k + 2) * NEXP + e], s2);
            s3 = fmaf(xr[k + 3], secret[(size_t)(k + 3) * NEXP + e], s3);
        }
        m = safe ? ((s0 + s1) + (s2 + s3)) : NEG_INF;
        v1 = m; e1 = e;
        #pragma unroll
        for (int off = 32; off; off >>= 1) {
            const float ov = __shfl_xor(v1, off); const int oi = __shfl_xor(e1, off);
            if (ov > v1 || (ov == v1 && oi < e1)) { v1 = ov; e1 = oi; }
        }
        v2 = (e == e1) ? -3.0e38f : m; e2 = e;
        #pragma unroll
        for (int off = 32; off; off >>= 1) {
            const float ov = __shfl_xor(v2, off); const int oi = __shfl_xor(e2, off);
            if (ov > v2 || (ov == v2 && oi < e2)) { v2 = ov; e2 = oi; }
        }
    }

    const float l1 = __shfl(raw, e1);
    const float l2 = __shfl(raw, e2);

    if (e == 0) {
        const float mm = fmaxf(l1, l2);
        const float x1 = expf(l1 - mm), x2 = expf(l2 - mm);
        const float inv = 1.0f / (x1 + x2);
        out[(size_t)t * 2 + 0] = x1 * inv;
        out[(size_t)t * 2 + 1] = x2 * inv;
        out[(size_t)2 * ntok + t * 2 + 0] = (float)e1;
        out[(size_t)2 * ntok + t * 2 + 1] = (float)e2;
    }
}

extern "C" void kernel_launch(void* const* d_in, const int* in_sizes, int n_in,
                              void* d_out, int out_size, void* d_ws, size_t ws_size,
                              hipStream_t stream) {
    const float* x      = (const float*)d_in[0];
    const float* gateW  = (const float*)d_in[1];
    const float* secret = (const float*)d_in[2];
    float* out = (float*)d_out;

    const int ntok = in_sizes[0] / DDIM;                 // 16384
    uint4* wsB = (uint4*)d_ws;                           // 1 MB fragments
    float* wsP = (float*)((char*)d_ws + (2u << 20));     // partials [4][ntok][128]

    prep_b<<<64, 512, 0, stream>>>(gateW, secret, wsB);
    gemm_r<<<(ntok / 256) * KSPL, 256, 0, stream>>>(x, wsB, wsP, ntok);
    router_k<KSPL><<<ntok / 4, 256, 0, stream>>>(wsP, x, gateW, secret, out, ntok);
}

// Round 16
// 94.966 us; speedup vs baseline: 1.2794x; 1.2794x over previous
//
#include <hip/hip_runtime.h>
#include <stdint.h>

// OKRRouter, split-bf16 MFMA, 3 slim kernels — ROUND-10 KNOWN-GOOD RESTORE (94.76 us).
// K1 prep_b:  gate_W^T | secret -> bf16 hi/lo fragment-linear layout in ws (1 MB, L2-resident).
// K2 gemm_p:  grid split-K=4; 512 thr = 8 waves = 128 tokens/block; 2 blocks/CU.
//             Per K-step stage 32 KB into double-buffered LDS via global_load_lds(16B) ONLY
//             (B fragments 16 KB + A tile 16 KB, A XOR-swizzled both-sides within 128B rows).
//             No register-destined global loads in the loop; one vmcnt(0) + s_barrier per step.
// K3 router_k: 1 wave/token; sums 4 partials; mask/top-2/softmax + margin-guarded exact
//             fp32 recompute (validated rounds 3-14).
// Post-crash policy: the asm register-pipeline direction (r15) is abandoned; this restores
// the session's best passing configuration.

#define DDIM 2048
#define NEXP 64
#define TOKB 128
#define KSPL 4
#define NTS  16          // (DDIM/KSPL)/32
#define NEG_INF  -1000000000.0f
#define MRG_RAW  0.04f
#define MRG_WM   0.15f

typedef __attribute__((ext_vector_type(8))) short bf16x8;
typedef __attribute__((ext_vector_type(4))) float f32x4;

union BFrag { bf16x8 v; uint32_t w[4]; uint4 q; };

// ---- RNE hi/lo split (prep_b only) ----
__device__ inline void split8_rne(const float* a, bf16x8* hi, bf16x8* lo) {
    BFrag h, l;
    #pragma unroll
    for (int p = 0; p < 4; ++p) {
        const uint32_t u0 = __float_as_uint(a[2*p]);
        const uint32_t u1 = __float_as_uint(a[2*p+1]);
        const uint32_t h0 = (u0 + 0x7FFFu + ((u0 >> 16) & 1u)) >> 16;
        const uint32_t h1 = (u1 + 0x7FFFu + ((u1 >> 16) & 1u)) >> 16;
        const float r0 = a[2*p]   - __uint_as_float(h0 << 16);
        const float r1 = a[2*p+1] - __uint_as_float(h1 << 16);
        const uint32_t v0 = __float_as_uint(r0);
        const uint32_t v1 = __float_as_uint(r1);
        const uint32_t l0 = (v0 + 0x7FFFu + ((v0 >> 16) & 1u)) >> 16;
        const uint32_t l1 = (v1 + 0x7FFFu + ((v1 >> 16) & 1u)) >> 16;
        h.w[p] = h0 | (h1 << 16);
        l.w[p] = l0 | (l1 << 16);
    }
    *hi = h.v; *lo = l.v;
}

// ---- cheap truncation split for the A stream (validated rounds 4-14) ----
__device__ inline void split8t(const float* a, bf16x8* hi, bf16x8* lo) {
    BFrag h, l;
    #pragma unroll
    for (int p = 0; p < 4; ++p) {
        const uint32_t u0 = __float_as_uint(a[2*p]);
        const uint32_t u1 = __float_as_uint(a[2*p+1]);
        h.w[p] = (u0 >> 16) | (u1 & 0xFFFF0000u);
        const float r0 = a[2*p]   - __uint_as_float(u0 & 0xFFFF0000u);
        const float r1 = a[2*p+1] - __uint_as_float(u1 & 0xFFFF0000u);
        l.w[p] = (__float_as_uint(r0) >> 16) | (__float_as_uint(r1) & 0xFFFF0000u);
    }
    *hi = h.v; *lo = l.v;
}

// ---- K1: B' fragments. frag f = kstep*8+s is 128 slots of 16B: 64 lanes hi, 64 lanes lo.
// lane l holds B[kstep*32 + (l>>4)*8 + j][s*16 + (l&15)], j=0..7
__global__ void prep_b(const float* __restrict__ gateW, const float* __restrict__ secret,
                       uint4* __restrict__ wsB) {
    const int kstep = blockIdx.x;            // 0..63
    const int s = threadIdx.x >> 6;          // 0..7
    const int l = threadIdx.x & 63;
    const int col = s * 16 + (l & 15);
    const int kb  = kstep * 32 + (l >> 4) * 8;
    float v[8];
    if (col < NEXP) {
        #pragma unroll
        for (int j = 0; j < 8; ++j) v[j] = gateW[(size_t)col * DDIM + kb + j];
    } else {
        #pragma unroll
        for (int j = 0; j < 8; ++j) v[j] = secret[(size_t)(kb + j) * NEXP + (col - NEXP)];
    }
    bf16x8 hi, lo; split8_rne(v, &hi, &lo);
    const size_t base = (size_t)(kstep * 8 + s) * 128 + l;
    BFrag t;
    t.v = hi; wsB[base]      = t.q;
    t.v = lo; wsB[base + 64] = t.q;
}

// ---- async global->LDS, 16B per lane ----
__device__ inline void gl_lds16(const char* g, char* l) {
    __builtin_amdgcn_global_load_lds(
        (const __attribute__((address_space(1))) void*)g,
        (__attribute__((address_space(3))) void*)l, 16, 0, 0);
}

// ---- K2: GEMM, everything staged via global_load_lds ----
__global__ __launch_bounds__(512, 4)   // 4 waves/EU -> 2 blocks/CU (512 thr = 8 waves)
void gemm_p(const float* __restrict__ x, const char* __restrict__ wsB,
            float* __restrict__ wsP, int ntok)
{
    // per buffer: [0,16384) = 16 B-frags x 1 KB ; [16384,32768) = A tile 128 rows x 128 B
    __shared__ __align__(16) char lds[2][32768];

    const int tid = threadIdx.x;
    const int w = tid >> 6, l = tid & 63;
    const int c = l & 15;              // token within wave tile / frag col
    const int g = l >> 4;              // k-group / C-row group
    const int q  = blockIdx.x & (KSPL - 1);
    const int mb = blockIdx.x / KSPL;
    const int rowbase = mb * TOKB;     // block token base
    const int wrow = rowbase + w * 16; // wave token base

    f32x4 acc[8];
    #pragma unroll
    for (int s = 0; s < 8; ++s) acc[s] = (f32x4){0.f, 0.f, 0.f, 0.f};

    const char*  bq = wsB + (size_t)(q * NTS) * 16384;   // this quarter's B frag-sets
    const float* xq = x + q * (DDIM / KSPL);             // this quarter's K offset

    // stage step ts into buf: 2048 slots x 16B, 4 gl_lds16/thread.
    // B slots 0..1023: slot = i*64 + lane (i = frag 0..15) — matches wsB layout.
    // A slots 1024..2047: a = slot-1024; row r = a>>3, col-grp cg = a&7;
    //   LDS slot (r,cg) holds SOURCE col-grp (cg ^ (r&7))  [XOR swizzle, within 128B row].
    #define STAGE(ts, buf)                                                         \
        {                                                                          \
            _Pragma("unroll")                                                      \
            for (int j = 0; j < 2; ++j) {                                          \
                const int slot = j * 512 + tid;                                    \
                const int i = slot >> 6;                                           \
                gl_lds16(bq + (size_t)(ts) * 16384 + i * 1024 + l * 16,            \
                         &lds[buf][slot * 16]);                                    \
            }                                                                      \
            _Pragma("unroll")                                                      \
            for (int j = 0; j < 2; ++j) {                                          \
                const int a = j * 512 + tid;                                       \
                const int r = a >> 3, cg = a & 7;                                  \
                const int scg = cg ^ (r & 7);                                      \
                gl_lds16((const char*)(xq + (size_t)(rowbase + r) * DDIM           \
                                       + (ts) * 32 + scg * 4),                     \
                         &lds[buf][16384 + a * 16]);                               \
            }                                                                      \
        }

    STAGE(0, 0);
    asm volatile("s_waitcnt vmcnt(0)" ::: "memory");
    __builtin_amdgcn_s_barrier();

    #pragma unroll 1
    for (int ts = 0; ts < NTS; ++ts) {
        const int cur = ts & 1;
        const int nts = (ts + 1 < NTS) ? ts + 1 : ts;   // clamped dummy restage at tail
        STAGE(nts, cur ^ 1);                            // issue next step FIRST

        // ---- A from LDS (swizzled read), split in-register ----
        const char* ab = &lds[cur][16384];
        const int r = w * 16 + c;
        const int s0 = (2 * g)     ^ (r & 7);
        const int s1 = (2 * g + 1) ^ (r & 7);
        const float4 fa = *reinterpret_cast<const float4*>(ab + r * 128 + s0 * 16);
        const float4 fb = *reinterpret_cast<const float4*>(ab + r * 128 + s1 * 16);
        const float va[8] = {fa.x, fa.y, fa.z, fa.w, fb.x, fb.y, fb.z, fb.w};
        bf16x8 ah, al;
        split8t(va, &ah, &al);

        // ---- B frags + MFMA ----
        const char* bb = lds[cur];
        #pragma unroll
        for (int s = 0; s < 8; ++s) {
            const bf16x8 bh = *reinterpret_cast<const bf16x8*>(bb + (2*s)     * 1024 + l * 16);
            const bf16x8 bl = *reinterpret_cast<const bf16x8*>(bb + (2*s + 1) * 1024 + l * 16);
            acc[s] = __builtin_amdgcn_mfma_f32_16x16x32_bf16(ah, bh, acc[s], 0, 0, 0);
            acc[s] = __builtin_amdgcn_mfma_f32_16x16x32_bf16(ah, bl, acc[s], 0, 0, 0);
            acc[s] = __builtin_amdgcn_mfma_f32_16x16x32_bf16(al, bh, acc[s], 0, 0, 0);
        }

        asm volatile("s_waitcnt vmcnt(0)" ::: "memory");
        __builtin_amdgcn_s_barrier();
    }
    #undef STAGE

    // partials: C/D layout row = (l>>4)*4 + reg, col = l&15
    const size_t MN = (size_t)ntok * 128;
    #pragma unroll
    for (int s = 0; s < 8; ++s)
        #pragma unroll
        for (int r = 0; r < 4; ++r)
            wsP[(size_t)q * MN + (size_t)(wrow + g * 4 + r) * 128 + s * 16 + c] = acc[s][r];
}

// ---- K3: router, 1 wave per token, sums KSPL partials (validated rounds 2-14) ----
template <int KSPLIT>
__global__ __launch_bounds__(256, 4)
void router_k(const float* __restrict__ wsP,
              const float* __restrict__ x,
              const float* __restrict__ gateW,
              const float* __restrict__ secret,
              float* __restrict__ out, int ntok)
{
    const int t = blockIdx.x * 4 + (threadIdx.x >> 6);
    const int e = threadIdx.x & 63;
    const size_t MN = (size_t)ntok * 128;

    float raw = 0.f, wm = 0.f;
    #pragma unroll
    for (int q = 0; q < KSPLIT; ++q) {
        raw += wsP[(size_t)q * MN + (size_t)t * 128 + e];
        wm  += wsP[(size_t)q * MN + (size_t)t * 128 + NEXP + e];
    }

    float rmax = raw;
    #pragma unroll
    for (int off = 32; off; off >>= 1) rmax = fmaxf(rmax, __shfl_xor(rmax, off));

    // guard 1: safe-mask boundary margin -> exact fp32 raw recompute (whole token)
    if (__any(fabsf(raw - (rmax - 1.5f)) < MRG_RAW)) {
        float s0 = 0.f, s1 = 0.f, s2 = 0.f, s3 = 0.f;
        const float4* xr = reinterpret_cast<const float4*>(x + (size_t)t * DDIM);
        const float4* wr = reinterpret_cast<const float4*>(gateW + (size_t)e * DDIM);
        for (int k = 0; k < DDIM / 4; ++k) {
            const float4 a = xr[k], b = wr[k];
            s0 = fmaf(a.x, b.x, s0); s1 = fmaf(a.y, b.y, s1);
            s2 = fmaf(a.z, b.z, s2); s3 = fmaf(a.w, b.w, s3);
        }
        raw = (s0 + s1) + (s2 + s3);
        rmax = raw;
        #pragma unroll
        for (int off = 32; off; off >>= 1) rmax = fmaxf(rmax, __shfl_xor(rmax, off));
    }

    const bool safe = (raw >= rmax - 1.5f);
    float m = safe ? wm : NEG_INF;

    // top-3 (value desc, lowest index on ties = jax.lax.top_k)
    float v1 = m; int e1 = e;
    #pragma unroll
    for (int off = 32; off; off >>= 1) {
        const float ov = __shfl_xor(v1, off); const int oi = __shfl_xor(e1, off);
        if (ov > v1 || (ov == v1 && oi < e1)) { v1 = ov; e1 = oi; }
    }
    float v2 = (e == e1) ? -3.0e38f : m; int e2 = e;
    #pragma unroll
    for (int off = 32; off; off >>= 1) {
        const float ov = __shfl_xor(v2, off); const int oi = __shfl_xor(e2, off);
        if (ov > v2 || (ov == v2 && oi < e2)) { v2 = ov; e2 = oi; }
    }
    float v3 = (e == e1 || e == e2) ? -3.0e38f : m; int e3 = e;
    #pragma unroll
    for (int off = 32; off; off >>= 1) {
        const float ov = __shfl_xor(v3, off); const int oi = __shfl_xor(e3, off);
        if (ov > v3 || (ov == v3 && oi < e3)) { v3 = ov; e3 = oi; }
    }

    // guard 2: close wm ordering among safe candidates -> exact fp32 wm recompute
    const bool wmRisk = (v2 > NEG_INF + 1.0f && v1 - v2 < MRG_WM) ||
                        (v3 > NEG_INF + 1.0f && v2 - v3 < MRG_WM);
    if (__any(wmRisk)) {
        float s0 = 0.f, s1 = 0.f, s2 = 0.f, s3 = 0.f;
        const float* xr = x + (size_t)t * DDIM;
        for (int k = 0; k < DDIM; k += 4) {
            s0 = fmaf(xr[k + 0], secret[(size_t)(k + 0) * NEXP + e], s0);
            s1 = fmaf(xr[k + 1], secret[(size_t)(k + 1) * NEXP + e], s1);
            s2 = fmaf(xr[k + 2], secret[(size_t)(k + 2) * NEXP + e], s2);
            s3 = fmaf(xr[k + 3], secret[(size_t)(k + 3) * NEXP + e], s3);
        }
        m = safe ? ((s0 + s1) + (s2 + s3)) : NEG_INF;
        v1 = m; e1 = e;
        #pragma unroll
        for (int off = 32; off; off >>= 1) {
            const float ov = __shfl_xor(v1, off); const int oi = __shfl_xor(e1, off);
            if (ov > v1 || (ov == v1 && oi < e1)) { v1 = ov; e1 = oi; }
        }
        v2 = (e == e1) ? -3.0e38f : m; e2 = e;
        #pragma unroll
        for (int off = 32; off; off >>= 1) {
            const float ov = __shfl_xor(v2, off); const int oi = __shfl_xor(e2, off);
            if (ov > v2 || (ov == v2 && oi < e2)) { v2 = ov; e2 = oi; }
        }
    }

    const float l1 = __shfl(raw, e1);
    const float l2 = __shfl(raw, e2);

    if (e == 0) {
        const float mm = fmaxf(l1, l2);
        const float x1 = expf(l1 - mm), x2 = expf(l2 - mm);
        const float inv = 1.0f / (x1 + x2);
        out[(size_t)t * 2 + 0] = x1 * inv;
        out[(size_t)t * 2 + 1] = x2 * inv;
        out[(size_t)2 * ntok + t * 2 + 0] = (float)e1;
        out[(size_t)2 * ntok + t * 2 + 1] = (float)e2;
    }
}

extern "C" void kernel_launch(void* const* d_in, const int* in_sizes, int n_in,
                              void* d_out, int out_size, void* d_ws, size_t ws_size,
                              hipStream_t stream) {
    const float* x      = (const float*)d_in[0];
    const float* gateW  = (const float*)d_in[1];
    const float* secret = (const float*)d_in[2];
    float* out = (float*)d_out;

    const int ntok = in_sizes[0] / DDIM;                 // 16384
    uint4* wsB = (uint4*)d_ws;                           // 1 MB fragments
    float* wsP = (float*)((char*)d_ws + (2u << 20));     // partials [4][ntok][128]

    prep_b<<<64, 512, 0, stream>>>(gateW, secret, wsB);
    gemm_p<<<(ntok / TOKB) * KSPL, 512, 0, stream>>>(x, (const char*)wsB, wsP, ntok);
    router_k<KSPL><<<ntok / 4, 256, 0, stream>>>(wsP, x, gateW, secret, out, ntok);
}

// Round 17
// 94.227 us; speedup vs baseline: 1.2894x; 1.0078x over previous
//
#include <hip/hip_runtime.h>
#include <stdint.h>

// OKRRouter, split-bf16 MFMA, 3 slim kernels.
// K2 gemm_m2: r16 structure with 2 M-tiles per wave (32 tokens) — each B fragment read
//   from LDS feeds 6 MFMAs (both M-tiles) instead of 3. LDS port traffic per 128-token
//   block-step: 176 KB -> 112 KB (the r12 ablation + per-inst sizing shows the loop is
//   LDS-port-BW bound: ds_read_b128 moves 1 KB/inst; 8 waves re-reading the B tile was
//   8x amplification). Geometry: 256 thr / 4 waves, TOKB=128, KSPL=4, grid 512,
//   64 KB dbuf LDS, 2 blocks/CU. Staging via global_load_lds(16B) only; one
//   vmcnt(0)+s_barrier per step (r16-proven).
// K3 router_k: 1 wave/token; sums 4 partials; margin-guarded exact fp32 recompute
//   (validated rounds 3-16).

#define DDIM 2048
#define NEXP 64
#define TOKB 128
#define KSPL 4
#define NTS  16          // (DDIM/KSPL)/32
#define NEG_INF  -1000000000.0f
#define MRG_RAW  0.04f
#define MRG_WM   0.15f

typedef __attribute__((ext_vector_type(8))) short bf16x8;
typedef __attribute__((ext_vector_type(4))) float f32x4;

union BFrag { bf16x8 v; uint32_t w[4]; uint4 q; };

// ---- RNE hi/lo split (prep_b only) ----
__device__ inline void split8_rne(const float* a, bf16x8* hi, bf16x8* lo) {
    BFrag h, l;
    #pragma unroll
    for (int p = 0; p < 4; ++p) {
        const uint32_t u0 = __float_as_uint(a[2*p]);
        const uint32_t u1 = __float_as_uint(a[2*p+1]);
        const uint32_t h0 = (u0 + 0x7FFFu + ((u0 >> 16) & 1u)) >> 16;
        const uint32_t h1 = (u1 + 0x7FFFu + ((u1 >> 16) & 1u)) >> 16;
        const float r0 = a[2*p]   - __uint_as_float(h0 << 16);
        const float r1 = a[2*p+1] - __uint_as_float(h1 << 16);
        const uint32_t v0 = __float_as_uint(r0);
        const uint32_t v1 = __float_as_uint(r1);
        const uint32_t l0 = (v0 + 0x7FFFu + ((v0 >> 16) & 1u)) >> 16;
        const uint32_t l1 = (v1 + 0x7FFFu + ((v1 >> 16) & 1u)) >> 16;
        h.w[p] = h0 | (h1 << 16);
        l.w[p] = l0 | (l1 << 16);
    }
    *hi = h.v; *lo = l.v;
}

// ---- cheap truncation split for the A stream (validated rounds 4-16) ----
__device__ inline void split8t(const float* a, bf16x8* hi, bf16x8* lo) {
    BFrag h, l;
    #pragma unroll
    for (int p = 0; p < 4; ++p) {
        const uint32_t u0 = __float_as_uint(a[2*p]);
        const uint32_t u1 = __float_as_uint(a[2*p+1]);
        h.w[p] = (u0 >> 16) | (u1 & 0xFFFF0000u);
        const float r0 = a[2*p]   - __uint_as_float(u0 & 0xFFFF0000u);
        const float r1 = a[2*p+1] - __uint_as_float(u1 & 0xFFFF0000u);
        l.w[p] = (__float_as_uint(r0) >> 16) | (__float_as_uint(r1) & 0xFFFF0000u);
    }
    *hi = h.v; *lo = l.v;
}

// ---- K1: B' fragments. frag f = kstep*8+s is 128 slots of 16B: 64 lanes hi, 64 lanes lo.
// lane l holds B[kstep*32 + (l>>4)*8 + j][s*16 + (l&15)], j=0..7
__global__ void prep_b(const float* __restrict__ gateW, const float* __restrict__ secret,
                       uint4* __restrict__ wsB) {
    const int kstep = blockIdx.x;            // 0..63
    const int s = threadIdx.x >> 6;          // 0..7
    const int l = threadIdx.x & 63;
    const int col = s * 16 + (l & 15);
    const int kb  = kstep * 32 + (l >> 4) * 8;
    float v[8];
    if (col < NEXP) {
        #pragma unroll
        for (int j = 0; j < 8; ++j) v[j] = gateW[(size_t)col * DDIM + kb + j];
    } else {
        #pragma unroll
        for (int j = 0; j < 8; ++j) v[j] = secret[(size_t)(kb + j) * NEXP + (col - NEXP)];
    }
    bf16x8 hi, lo; split8_rne(v, &hi, &lo);
    const size_t base = (size_t)(kstep * 8 + s) * 128 + l;
    BFrag t;
    t.v = hi; wsB[base]      = t.q;
    t.v = lo; wsB[base + 64] = t.q;
}

// ---- async global->LDS, 16B per lane ----
__device__ inline void gl_lds16(const char* g, char* l) {
    __builtin_amdgcn_global_load_lds(
        (const __attribute__((address_space(1))) void*)g,
        (__attribute__((address_space(3))) void*)l, 16, 0, 0);
}

// ---- K2: GEMM, 2 M-tiles per wave, everything staged via global_load_lds ----
__global__ __launch_bounds__(256, 2)
void gemm_m2(const float* __restrict__ x, const char* __restrict__ wsB,
             float* __restrict__ wsP, int ntok)
{
    // per buffer: [0,16384) = 16 B-frags x 1 KB ; [16384,32768) = A tile 128 rows x 128 B
    __shared__ __align__(16) char lds[2][32768];

    const int tid = threadIdx.x;
    const int w = tid >> 6, l = tid & 63;
    const int c = l & 15;              // token within 16-tile / frag col
    const int g = l >> 4;              // k-group / C-row group
    const int q  = blockIdx.x & (KSPL - 1);
    const int mb = blockIdx.x / KSPL;
    const int rowbase = mb * TOKB;     // block token base
    const int wrow = rowbase + w * 32; // wave token base (2 M-tiles of 16)

    f32x4 acc[2][8];
    #pragma unroll
    for (int m = 0; m < 2; ++m)
        #pragma unroll
        for (int s = 0; s < 8; ++s) acc[m][s] = (f32x4){0.f, 0.f, 0.f, 0.f};

    const char*  bq = wsB + (size_t)(q * NTS) * 16384;   // this quarter's B frag-sets
    const float* xq = x + q * (DDIM / KSPL);             // this quarter's K offset

    // stage step ts into buf: 2048 slots x 16B, 8 gl_lds16/thread (256 thr).
    // B slots 0..1023: slot = i*64 + lane (i = frag 0..15) — matches wsB layout.
    // A slots 1024..2047: a = slot-1024; row r = a>>3, col-grp cg = a&7;
    //   LDS slot (r,cg) holds SOURCE col-grp (cg ^ (r&7))  [XOR swizzle, within 128B row].
    #define STAGE(ts, buf)                                                         \
        {                                                                          \
            _Pragma("unroll")                                                      \
            for (int j = 0; j < 4; ++j) {                                          \
                const int slot = j * 256 + tid;                                    \
                const int i = slot >> 6;                                           \
                gl_lds16(bq + (size_t)(ts) * 16384 + i * 1024 + l * 16,            \
                         &lds[buf][slot * 16]);                                    \
            }                                                                      \
            _Pragma("unroll")                                                      \
            for (int j = 0; j < 4; ++j) {                                          \
                const int a = j * 256 + tid;                                       \
                const int r = a >> 3, cg = a & 7;                                  \
                const int scg = cg ^ (r & 7);                                      \
                gl_lds16((const char*)(xq + (size_t)(rowbase + r) * DDIM           \
                                       + (ts) * 32 + scg * 4),                     \
                         &lds[buf][16384 + a * 16]);                               \
            }                                                                      \
        }

    STAGE(0, 0);
    asm volatile("s_waitcnt vmcnt(0)" ::: "memory");
    __builtin_amdgcn_s_barrier();

    #pragma unroll 1
    for (int ts = 0; ts < NTS; ++ts) {
        const int cur = ts & 1;
        const int nts = (ts + 1 < NTS) ? ts + 1 : ts;   // clamped dummy restage at tail
        STAGE(nts, cur ^ 1);                            // issue next step FIRST

        // ---- A from LDS (swizzled read), split in-register; 2 M-tiles ----
        const char* ab = &lds[cur][16384];
        bf16x8 ah[2], al[2];
        #pragma unroll
        for (int m = 0; m < 2; ++m) {
            const int r = w * 32 + m * 16 + c;
            const int s0 = (2 * g)     ^ (r & 7);
            const int s1 = (2 * g + 1) ^ (r & 7);
            const float4 fa = *reinterpret_cast<const float4*>(ab + r * 128 + s0 * 16);
            const float4 fb = *reinterpret_cast<const float4*>(ab + r * 128 + s1 * 16);
            const float va[8] = {fa.x, fa.y, fa.z, fa.w, fb.x, fb.y, fb.z, fb.w};
            split8t(va, &ah[m], &al[m]);
        }

        // ---- B frags (read ONCE, feed both M-tiles) + MFMA ----
        const char* bb = lds[cur];
        #pragma unroll
        for (int s = 0; s < 8; ++s) {
            const bf16x8 bh = *reinterpret_cast<const bf16x8*>(bb + (2*s)     * 1024 + l * 16);
            const bf16x8 bl = *reinterpret_cast<const bf16x8*>(bb + (2*s + 1) * 1024 + l * 16);
            #pragma unroll
            for (int m = 0; m < 2; ++m) {
                acc[m][s] = __builtin_amdgcn_mfma_f32_16x16x32_bf16(ah[m], bh, acc[m][s], 0, 0, 0);
                acc[m][s] = __builtin_amdgcn_mfma_f32_16x16x32_bf16(ah[m], bl, acc[m][s], 0, 0, 0);
                acc[m][s] = __builtin_amdgcn_mfma_f32_16x16x32_bf16(al[m], bh, acc[m][s], 0, 0, 0);
            }
        }

        asm volatile("s_waitcnt vmcnt(0)" ::: "memory");
        __builtin_amdgcn_s_barrier();
    }
    #undef STAGE

    // partials: C/D layout row = (l>>4)*4 + reg, col = l&15
    const size_t MN = (size_t)ntok * 128;
    #pragma unroll
    for (int m = 0; m < 2; ++m)
        #pragma unroll
        for (int s = 0; s < 8; ++s)
            #pragma unroll
            for (int r = 0; r < 4; ++r)
                wsP[(size_t)q * MN + (size_t)(wrow + m * 16 + g * 4 + r) * 128 + s * 16 + c]
                    = acc[m][s][r];
}

// ---- K3: router, 1 wave per token, sums KSPL partials (validated rounds 2-16) ----
template <int KSPLIT>
__global__ __launch_bounds__(256, 4)
void router_k(const float* __restrict__ wsP,
              const float* __restrict__ x,
              const float* __restrict__ gateW,
              const float* __restrict__ secret,
              float* __restrict__ out, int ntok)
{
    const int t = blockIdx.x * 4 + (threadIdx.x >> 6);
    const int e = threadIdx.x & 63;
    const size_t MN = (size_t)ntok * 128;

    float raw = 0.f, wm = 0.f;
    #pragma unroll
    for (int q = 0; q < KSPLIT; ++q) {
        raw += wsP[(size_t)q * MN + (size_t)t * 128 + e];
        wm  += wsP[(size_t)q * MN + (size_t)t * 128 + NEXP + e];
    }

    float rmax = raw;
    #pragma unroll
    for (int off = 32; off; off >>= 1) rmax = fmaxf(rmax, __shfl_xor(rmax, off));

    // guard 1: safe-mask boundary margin -> exact fp32 raw recompute (whole token)
    if (__any(fabsf(raw - (rmax - 1.5f)) < MRG_RAW)) {
        float s0 = 0.f, s1 = 0.f, s2 = 0.f, s3 = 0.f;
        const float4* xr = reinterpret_cast<const float4*>(x + (size_t)t * DDIM);
        const float4* wr = reinterpret_cast<const float4*>(gateW + (size_t)e * DDIM);
        for (int k = 0; k < DDIM / 4; ++k) {
            const float4 a = xr[k], b = wr[k];
            s0 = fmaf(a.x, b.x, s0); s1 = fmaf(a.y, b.y, s1);
            s2 = fmaf(a.z, b.z, s2); s3 = fmaf(a.w, b.w, s3);
        }
        raw = (s0 + s1) + (s2 + s3);
        rmax = raw;
        #pragma unroll
        for (int off = 32; off; off >>= 1) rmax = fmaxf(rmax, __shfl_xor(rmax, off));
    }

    const bool safe = (raw >= rmax - 1.5f);
    float m = safe ? wm : NEG_INF;

    // top-3 (value desc, lowest index on ties = jax.lax.top_k)
    float v1 = m; int e1 = e;
    #pragma unroll
    for (int off = 32; off; off >>= 1) {
        const float ov = __shfl_xor(v1, off); const int oi = __shfl_xor(e1, off);
        if (ov > v1 || (ov == v1 && oi < e1)) { v1 = ov; e1 = oi; }
    }
    float v2 = (e == e1) ? -3.0e38f : m; int e2 = e;
    #pragma unroll
    for (int off = 32; off; off >>= 1) {
        const float ov = __shfl_xor(v2, off); const int oi = __shfl_xor(e2, off);
        if (ov > v2 || (ov == v2 && oi < e2)) { v2 = ov; e2 = oi; }
    }
    float v3 = (e == e1 || e == e2) ? -3.0e38f : m; int e3 = e;
    #pragma unroll
    for (int off = 32; off; off >>= 1) {
        const float ov = __shfl_xor(v3, off); const int oi = __shfl_xor(e3, off);
        if (ov > v3 || (ov == v3 && oi < e3)) { v3 = ov; e3 = oi; }
    }

    // guard 2: close wm ordering among safe candidates -> exact fp32 wm recompute
    const bool wmRisk = (v2 > NEG_INF + 1.0f && v1 - v2 < MRG_WM) ||
                        (v3 > NEG_INF + 1.0f && v2 - v3 < MRG_WM);
    if (__any(wmRisk)) {
        float s0 = 0.f, s1 = 0.f, s2 = 0.f, s3 = 0.f;
        const float* xr = x + (size_t)t * DDIM;
        for (int k = 0; k < DDIM; k += 4) {
            s0 = fmaf(xr[k + 0], secret[(size_t)(k + 0) * NEXP + e], s0);
            s1 = fmaf(xr[k + 1], secret[(size_t)(k + 1) * NEXP + e], s1);
            s2 = fmaf(xr[k + 2], secret[(size_t)(k + 2) * NEXP + e], s2);
            s3 = fmaf(xr[k + 3], secret[(size_t)(k + 3) * NEXP + e], s3);
        }
        m = safe ? ((s0 + s1) + (s2 + s3)) : NEG_INF;
        v1 = m; e1 = e;
        #pragma unroll
        for (int off = 32; off; off >>= 1) {
            const float ov = __shfl_xor(v1, off); const int oi = __shfl_xor(e1, off);
            if (ov > v1 || (ov == v1 && oi < e1)) { v1 = ov; e1 = oi; }
        }
        v2 = (e == e1) ? -3.0e38f : m; e2 = e;
        #pragma unroll
        for (int off = 32; off; off >>= 1) {
            const float ov = __shfl_xor(v2, off); const int oi = __shfl_xor(e2, off);
            if (ov > v2 || (ov == v2 && oi < e2)) { v2 = ov; e2 = oi; }
        }
    }

    const float l1 = __shfl(raw, e1);
    const float l2 = __shfl(raw, e2);

    if (e == 0) {
        const float mm = fmaxf(l1, l2);
        const float x1 = expf(l1 - mm), x2 = expf(l2 - mm);
        const float inv = 1.0f / (x1 + x2);
        out[(size_t)t * 2 + 0] = x1 * inv;
        out[(size_t)t * 2 + 1] = x2 * inv;
        out[(size_t)2 * ntok + t * 2 + 0] = (float)e1;
        out[(size_t)2 * ntok + t * 2 + 1] = (float)e2;
    }
}

extern "C" void kernel_launch(void* const* d_in, const int* in_sizes, int n_in,
                              void* d_out, int out_size, void* d_ws, size_t ws_size,
                              hipStream_t stream) {
    const float* x      = (const float*)d_in[0];
    const float* gateW  = (const float*)d_in[1];
    const float* secret = (const float*)d_in[2];
    float* out = (float*)d_out;

    const int ntok = in_sizes[0] / DDIM;                 // 16384
    uint4* wsB = (uint4*)d_ws;                           // 1 MB fragments
    float* wsP = (float*)((char*)d_ws + (2u << 20));     // partials [4][ntok][128]

    prep_b<<<64, 512, 0, stream>>>(gateW, secret, wsB);
    gemm_m2<<<(ntok / TOKB) * KSPL, 256, 0, stream>>>(x, (const char*)wsB, wsP, ntok);
    router_k<KSPL><<<ntok / 4, 256, 0, stream>>>(wsP, x, gateW, secret, out, ntok);
}